// Round 12
// baseline (191.131 us; speedup 1.0000x reference)
//
#include <hip/hip_runtime.h>
#include <hip/hip_fp16.h>

// SoftNCutsLoss on MI355X — R12.
// batch: (4,1,32,32,32) f32, preds: (4,8,32,32,32) f32 -> out: (4,) f32
//
// R12 model (two-point fit R6/R9): time = fixed 48K cyc/CU + 32 cyc/wave-offset.
// Variable part is at the LDS+VALU floor (why R7/R10/R11 were neutral); the
// lever is the FIXED part = 4 blocks/CU x (scalar 9-plane staging + barrier +
// epilogue). R12: 256-voxel tiles (4x8x8), grid 512 -> 2 blocks/CU (fixed cost
// halves, halo amplification 7.7x -> 5.4x); staging vectorized with aligned
// float4 loads along w (9 dwordx4/task vs 36 dwords). No offset split: each
// thread owns one voxel, all 125 positive-lex offsets (math = R11, absmax 0.0).

#define EPS_F 2.220446049250313e-16f

constexpr int TD = 4, TH = 8, TW = 8;      // tile dims (d,h,w)
constexpr int HDh = 7, HHh = 14, HWh = 14; // halo: x forward-only +3, y/z +-3
constexpr int SYB = 17;                    // halo h-stride (odd: spreads banks)
constexpr int SXB = HHh * SYB;             // 238, halo d-stride
constexpr int NB  = 6 * SXB + 13 * SYB + 13 + 1;  // 1663 voxel slots
constexpr int NT = 256;                    // threads per block (4 waves)
constexpr int NBLK = 512;                  // 4 batches * 128 tiles
constexpr int NTASK = HDh * HHh * 4;       // 392 staging tasks (row x 4 chunks)

// exp(-s^2/16) for s^2 in {0,1,4,9} (pad-S path only)
#define EX0 1.0f
#define EX1 0.93941306281347578611f
#define EX4 0.77880078307140486825f
#define EX9 0.56978282473092302544f

// exponent folding: aff = exp2(d2*K1 + c2*K2)
#define K1F (-0.014426950408889634f)       // -0.01 * log2(e)
#define K2F (-0.09016844005556021f)        // -log2(e)/16

struct Ent { int off; float lw; };
struct Tab { Ent e[128]; int n; };

constexpr Tab make_tab() {
    Tab t{};
    t.n = 0;
    for (int dxq = 0; dxq < 4; ++dxq)
        for (int dyi = 0; dyi < 7; ++dyi)
            for (int dzi = 0; dzi < 7; ++dzi) {
                int dy = dyi - 3, dz = dzi - 3;
                if (dxq == 0) {                  // lexicographic positivity
                    if (dy < 0) continue;
                    if (dy == 0 && dz <= 0) continue;
                }
                int c2 = dxq * dxq + dy * dy + dz * dz;
                if (c2 >= 16) continue;          // ball cutoff
                t.e[t.n].off = dxq * SXB + dy * SYB + dz;
                t.e[t.n].lw  = (float)c2 * K2F;
                ++t.n;                           // n = 125
            }
    return t;
}
constexpr Tab TAB = make_tab();

__device__ __forceinline__ unsigned pack2(float a, float b) {
    return (unsigned)__half_as_ushort(__float2half(a)) |
           ((unsigned)__half_as_ushort(__float2half(b)) << 16);
}

__global__ __launch_bounds__(NT, 4)
void softncuts_main(const float* __restrict__ batch,
                    const float* __restrict__ preds,
                    float* __restrict__ partials) {
    __shared__ float sB[NB];            // batch halo, f32
    __shared__ uint4 sPk[NB];           // preds halo, 8 x f16 packed per voxel
    __shared__ float sRed[4][16];

    const int bid  = blockIdx.x;
    const int bb   = bid >> 7;          // batch index 0..3
    const int tile = bid & 127;
    const int tw = tile & 3;            // -> w0 = tw*8
    const int th = (tile >> 2) & 3;     // -> h0 = th*8
    const int td = tile >> 4;           // -> d0 = td*4
    const int d0 = td * TD, h0 = th * TH, w0 = tw * TW;

    const int tid = threadIdx.x;
    const int lw = tid & 7;             // 0..7
    const int lh = (tid >> 3) & 7;      // 0..7
    const int ld = tid >> 6;            // 0..3

    const float* bbase = batch + (size_t)bb * 32768;
    const float* pbase = preds + (size_t)bb * 8 * 32768;

    // ---- stage forward-x halo, float4-vectorized along w ----
    // chunk grid aligned to gw % 4 == 0: chunks start at w0-4+4c, hw = 4c-1+e.
    for (int t = tid; t < NTASK; t += NT) {
        const int c   = t & 3;
        const int row = t >> 2;
        const int hh  = row % HHh;
        const int hd  = row / HHh;
        const int gd  = d0 + hd;
        const int gh  = h0 + hh - 3;
        const int gw0 = w0 - 4 + c * 4;
        const int hwb = c * 4 - 1;
        const bool fast = (gd < 32) & ((unsigned)gh < 32u) & (gw0 >= 0) & (gw0 + 3 < 32);
        if (fast) {
            const int sidx = (gd * 32 + gh) * 32 + gw0;   // 16B-aligned
            float4 pv[9];
            pv[0] = *(const float4*)(bbase + sidx);
#pragma unroll
            for (int k = 0; k < 8; ++k)
                pv[k + 1] = *(const float4*)(pbase + sidx + k * 32768);
#pragma unroll
            for (int e = 0; e < 4; ++e) {
                const int hw = hwb + e;
                if (hw < 0 || hw >= HWh) continue;
                const int f = hd * SXB + hh * SYB + hw;
                sB[f] = ((const float*)&pv[0])[e];
                unsigned u[4];
#pragma unroll
                for (int k = 0; k < 4; ++k)
                    u[k] = pack2(((const float*)&pv[2 * k + 1])[e],
                                 ((const float*)&pv[2 * k + 2])[e]);
                sPk[f] = make_uint4(u[0], u[1], u[2], u[3]);
            }
        } else {
#pragma unroll
            for (int e = 0; e < 4; ++e) {
                const int hw = hwb + e;
                if (hw < 0 || hw >= HWh) continue;
                const int gw = gw0 + e;
                const bool in = (gd < 32) & ((unsigned)gh < 32u) & ((unsigned)gw < 32u);
                const int sidx = (gd * 32 + gh) * 32 + gw;
                const int f = hd * SXB + hh * SYB + hw;
                sB[f] = in ? bbase[sidx] : EPS_F;
                unsigned u[4];
#pragma unroll
                for (int k = 0; k < 4; ++k)
                    u[k] = pack2(in ? pbase[sidx + (2 * k) * 32768]     : 0.f,
                                 in ? pbase[sidx + (2 * k + 1) * 32768] : 0.f);
                sPk[f] = make_uint4(u[0], u[1], u[2], u[3]);
            }
        }
    }
    __syncthreads();

    // ---- own voxel values from GLOBAL f32 (full precision for b_own and q) ----
    const int gdo = d0 + ld, gho = h0 + lh, gwo = w0 + lw;
    const int sidx_own = (gdo * 32 + gho) * 32 + gwo;
    const float b_own = bbase[sidx_own];
    float q[8];
#pragma unroll
    for (int k = 0; k < 8; ++k) q[k] = pbase[sidx_own + k * 32768];

    const int vown = ld * SXB + (lh + 3) * SYB + (lw + 3);

    float acc[9];
#pragma unroll
    for (int i = 0; i < 9; ++i) acc[i] = 0.f;

    // ---- all 125 positive-lex offsets, batch-4 grouped ----
    constexpr int N = TAB.n, N4 = (N / 4) * 4;
#pragma unroll
    for (int i = 0; i < N4; i += 4) {
        float sb[4];
        uint4 pk[4];
#pragma unroll
        for (int j = 0; j < 4; ++j) {
            const int nv = vown + TAB.e[i + j].off;
            sb[j] = sB[nv];
            pk[j] = sPk[nv];
        }
#pragma unroll
        for (int j = 0; j < 4; ++j) {
            const float d = b_own - sb[j];
            const float aff =
                __builtin_amdgcn_exp2f(__builtin_fmaf(d * d, K1F, TAB.e[i + j].lw));
            acc[8] += aff;
            __half2 h[4];
            __builtin_memcpy(h, &pk[j], 16);
            acc[0] = __builtin_fmaf(aff, __half2float(__low2half(h[0])),  acc[0]);
            acc[1] = __builtin_fmaf(aff, __half2float(__high2half(h[0])), acc[1]);
            acc[2] = __builtin_fmaf(aff, __half2float(__low2half(h[1])),  acc[2]);
            acc[3] = __builtin_fmaf(aff, __half2float(__high2half(h[1])), acc[3]);
            acc[4] = __builtin_fmaf(aff, __half2float(__low2half(h[2])),  acc[4]);
            acc[5] = __builtin_fmaf(aff, __half2float(__high2half(h[2])), acc[5]);
            acc[6] = __builtin_fmaf(aff, __half2float(__low2half(h[3])),  acc[6]);
            acc[7] = __builtin_fmaf(aff, __half2float(__high2half(h[3])), acc[7]);
        }
    }
#pragma unroll
    for (int i = N4; i < N; ++i) {               // remainder (1)
        const int nv = vown + TAB.e[i].off;
        const float sb = sB[nv];
        const uint4 pk = sPk[nv];
        const float d = b_own - sb;
        const float aff =
            __builtin_amdgcn_exp2f(__builtin_fmaf(d * d, K1F, TAB.e[i].lw));
        acc[8] += aff;
        __half2 h[4];
        __builtin_memcpy(h, &pk, 16);
        acc[0] = __builtin_fmaf(aff, __half2float(__low2half(h[0])),  acc[0]);
        acc[1] = __builtin_fmaf(aff, __half2float(__high2half(h[0])), acc[1]);
        acc[2] = __builtin_fmaf(aff, __half2float(__low2half(h[1])),  acc[2]);
        acc[3] = __builtin_fmaf(aff, __half2float(__high2half(h[1])), acc[3]);
        acc[4] = __builtin_fmaf(aff, __half2float(__low2half(h[2])),  acc[4]);
        acc[5] = __builtin_fmaf(aff, __half2float(__high2half(h[2])), acc[5]);
        acc[6] = __builtin_fmaf(aff, __half2float(__low2half(h[3])),  acc[6]);
        acc[7] = __builtin_fmaf(aff, __half2float(__high2half(h[3])), acc[7]);
    }

    // ---- geometric pad sum S over lexicographically NEGATIVE OOB offsets ----
    float S = 0.f;
    const bool border = (d0 < 3) | (h0 < 3) | (h0 + TH > 29) | (w0 < 3) | (w0 + TW > 29);
    if (border) {
        constexpr float EXT[10] = {EX0, EX1, 0.f, 0.f, EX4, 0.f, 0.f, 0.f, 0.f, EX9};
        for (int dxi = 0; dxi < 7; ++dxi) {
            const int dx  = dxi - 3;
            const int dxx = dx * dx;
            const bool ind = (unsigned)(gdo + dx) < 32u;
            for (int dyi = 0; dyi < 7; ++dyi) {
                const int dy   = dyi - 3;
                const int c2xy = dxx + dy * dy;
                if (c2xy >= 16) continue;
                const float wxy = __expf((float)c2xy * -0.0625f);
                const bool inxy = ind & ((unsigned)(gho + dy) < 32u);
#pragma unroll
                for (int dzi = 0; dzi < 7; ++dzi) {
                    const int dz  = dzi - 3;
                    const int czz = dz * dz;
                    const bool neg = (dx < 0) || (dx == 0 && (dy < 0 || (dy == 0 && dz < 0)));
                    const bool valid = ((c2xy + czz) < 16) && neg;
                    const bool inall = inxy & ((unsigned)(gwo + dz) < 32u);
                    S += (valid && !inall) ? wxy * EXT[czz] : 0.f;
                }
            }
        }
    }
    const float db = b_own - EPS_F;
    const float selfpad = 1.f + S * __expf(db * db * -0.01f);

    // ---- per-lane contributions (each voxel owned by exactly one thread) ----
    float vals[16];
#pragma unroll
    for (int k = 0; k < 8; ++k) {
        vals[k]     = q[k] * (2.f * acc[k] + q[k]);
        vals[8 + k] = q[k] * (acc[8] + selfpad) + acc[k];
    }

#pragma unroll
    for (int i = 0; i < 16; ++i) {
        float s = vals[i];
        for (int off = 32; off; off >>= 1) s += __shfl_down(s, off);
        vals[i] = s;
    }
    const int wave = tid >> 6;
    const int lane = tid & 63;
    if (lane == 0) {
#pragma unroll
        for (int i = 0; i < 16; ++i) sRed[wave][i] = vals[i];
    }
    __syncthreads();
    if (tid < 16) {
        partials[tid * NBLK + bid] =
            sRed[0][tid] + sRed[1][tid] + sRed[2][tid] + sRed[3][tid];
    }
}

__global__ __launch_bounds__(1024)
void softncuts_finalize(const float* __restrict__ partials,
                        float* __restrict__ out) {
    __shared__ float red[64];
    const int tid = threadIdx.x;          // 0..1023
    const int group = tid >> 4;           // 0..63 = bb*16 + slot
    const int j0 = tid & 15;
    const int slot = group & 15;
    const int bb = group >> 4;

    const float* p = partials + slot * NBLK + bb * 128;   // 128 tiles per batch
    float s = 0.f;
#pragma unroll
    for (int k = 0; k < 8; ++k) s += p[j0 + 16 * k];
    for (int off = 8; off; off >>= 1) s += __shfl_down(s, off, 16);
    if (j0 == 0) red[group] = s;
    __syncthreads();

    if (tid < 4) {
        float accv = 0.f;
#pragma unroll
        for (int k = 0; k < 8; ++k)
            accv += red[tid * 16 + k] / red[tid * 16 + 8 + k];
        out[tid] = 8.0f - accv;
    }
}

extern "C" void kernel_launch(void* const* d_in, const int* in_sizes, int n_in,
                              void* d_out, int out_size, void* d_ws, size_t ws_size,
                              hipStream_t stream) {
    const float* batch = (const float*)d_in[0];
    const float* preds = (const float*)d_in[1];
    float* out      = (float*)d_out;
    float* partials = (float*)d_ws;   // 16*NBLK floats = 32 KB

    softncuts_main<<<dim3(NBLK), dim3(NT), 0, stream>>>(batch, preds, partials);
    softncuts_finalize<<<dim3(1), dim3(1024), 0, stream>>>(partials, out);
}

// Round 13
// 80.674 us; speedup vs baseline: 2.3692x; 2.3692x over previous
//
#include <hip/hip_runtime.h>
#include <hip/hip_fp16.h>

// SoftNCutsLoss on MI355X — R13.
// batch: (4,1,32,32,32) f32, preds: (4,8,32,32,32) f32 -> out: (4,) f32
//
// R13 = R12's fixed-cost-halving idea with R11's compiler-proven loop shape.
// R12 failure mode (from counters): single 125-entry constexpr table exceeded
// the unroll threshold -> loop stayed rolled -> table materialized per-thread
// in SCRATCH (WRITE_SIZE 280 MB, FETCH 157 MB, VALUBusy 7.7%). gfx950 lesson:
// keep constexpr-table loops <= ~64 unrolled iterations.
//  - 256-voxel tile (4x8x8), grid 512 -> 2 blocks/CU (staging+barrier+epilogue
//    instances halved; R6/R9 fit says fixed cost ~20us of the 33us main).
//  - NT=512, __launch_bounds__(512,4) -> 128 VGPR cap (no spill; R7's spill
//    was the (512,8) 64-cap). 16 waves/CU, same as R11.
//  - two threads per voxel, offsets split by parity tables (62/63 entries).
//  - staging float4-vectorized (9 x dwordx4 per task).
// Math identical to R11 (pairwise symmetry + negative-lex pad S, absmax 0.0).

#define EPS_F 2.220446049250313e-16f

constexpr int TD = 4, TH = 8, TW = 8;      // tile dims (d,h,w)
constexpr int HDh = 7, HHh = 14, HWh = 14; // halo: x forward-only +3, y/z +-3
constexpr int SYB = 17;                    // halo h-stride
constexpr int SXB = HHh * SYB;             // 238, halo d-stride
constexpr int NB  = 6 * SXB + 13 * SYB + 13 + 1;  // 1663 voxel slots
constexpr int NT = 512;                    // threads per block (8 waves)
constexpr int NBLK = 512;                  // 4 batches * 128 tiles
constexpr int NTASK = HDh * HHh * 4;       // 392 staging tasks (row x 4 chunks)

// exp(-s^2/16) for s^2 in {0,1,4,9} (pad-S path only)
#define EX0 1.0f
#define EX1 0.93941306281347578611f
#define EX4 0.77880078307140486825f
#define EX9 0.56978282473092302544f

// exponent folding: aff = exp2(d2*K1 + c2*K2)
#define K1F (-0.014426950408889634f)       // -0.01 * log2(e)
#define K2F (-0.09016844005556021f)        // -log2(e)/16

struct Ent { int off; float lw; };
struct Tab { Ent e[64]; int n; };

constexpr Tab make_tab(int half) {
    Tab t{};
    t.n = 0;
    for (int dxq = 0; dxq < 4; ++dxq)
        for (int dyi = 0; dyi < 7; ++dyi)
            for (int dzi = 0; dzi < 7; ++dzi) {
                int dy = dyi - 3, dz = dzi - 3;
                if (dxq == 0) {                  // lexicographic positivity
                    if (dy < 0) continue;
                    if (dy == 0 && dz <= 0) continue;
                }
                int c2 = dxq * dxq + dy * dy + dz * dz;
                if (c2 >= 16) continue;          // ball cutoff
                if (((dyi + dzi) & 1) != half) continue;
                t.e[t.n].off = dxq * SXB + dy * SYB + dz;
                t.e[t.n].lw  = (float)c2 * K2F;
                ++t.n;                           // 62 / 63
            }
    return t;
}
constexpr Tab TAB0 = make_tab(0);
constexpr Tab TAB1 = make_tab(1);

__device__ __forceinline__ unsigned pack2(float a, float b) {
    return (unsigned)__half_as_ushort(__float2half(a)) |
           ((unsigned)__half_as_ushort(__float2half(b)) << 16);
}

template <int HALF>
__device__ __forceinline__ void accum_pairs(const float* __restrict__ sB,
                                            const uint4* __restrict__ sPk,
                                            int vown, float b_own,
                                            float acc[9]) {
    constexpr Tab T = HALF ? TAB1 : TAB0;
    constexpr int N = HALF ? TAB1.n : TAB0.n;
    constexpr int N4 = (N / 4) * 4;

#pragma unroll
    for (int i = 0; i < N4; i += 4) {
        float sb[4];
        uint4 pk[4];
#pragma unroll
        for (int j = 0; j < 4; ++j) {
            const int nv = vown + T.e[i + j].off;
            sb[j] = sB[nv];
            pk[j] = sPk[nv];
        }
#pragma unroll
        for (int j = 0; j < 4; ++j) {
            const float d = b_own - sb[j];
            const float aff =
                __builtin_amdgcn_exp2f(__builtin_fmaf(d * d, K1F, T.e[i + j].lw));
            acc[8] += aff;
            __half2 h[4];
            __builtin_memcpy(h, &pk[j], 16);
            acc[0] = __builtin_fmaf(aff, __half2float(__low2half(h[0])),  acc[0]);
            acc[1] = __builtin_fmaf(aff, __half2float(__high2half(h[0])), acc[1]);
            acc[2] = __builtin_fmaf(aff, __half2float(__low2half(h[1])),  acc[2]);
            acc[3] = __builtin_fmaf(aff, __half2float(__high2half(h[1])), acc[3]);
            acc[4] = __builtin_fmaf(aff, __half2float(__low2half(h[2])),  acc[4]);
            acc[5] = __builtin_fmaf(aff, __half2float(__high2half(h[2])), acc[5]);
            acc[6] = __builtin_fmaf(aff, __half2float(__low2half(h[3])),  acc[6]);
            acc[7] = __builtin_fmaf(aff, __half2float(__high2half(h[3])), acc[7]);
        }
    }
#pragma unroll
    for (int i = N4; i < N; ++i) {               // remainder (<=3)
        const int nv = vown + T.e[i].off;
        const float sb = sB[nv];
        const uint4 pk = sPk[nv];
        const float d = b_own - sb;
        const float aff =
            __builtin_amdgcn_exp2f(__builtin_fmaf(d * d, K1F, T.e[i].lw));
        acc[8] += aff;
        __half2 h[4];
        __builtin_memcpy(h, &pk, 16);
        acc[0] = __builtin_fmaf(aff, __half2float(__low2half(h[0])),  acc[0]);
        acc[1] = __builtin_fmaf(aff, __half2float(__high2half(h[0])), acc[1]);
        acc[2] = __builtin_fmaf(aff, __half2float(__low2half(h[1])),  acc[2]);
        acc[3] = __builtin_fmaf(aff, __half2float(__high2half(h[1])), acc[3]);
        acc[4] = __builtin_fmaf(aff, __half2float(__low2half(h[2])),  acc[4]);
        acc[5] = __builtin_fmaf(aff, __half2float(__high2half(h[2])), acc[5]);
        acc[6] = __builtin_fmaf(aff, __half2float(__low2half(h[3])),  acc[6]);
        acc[7] = __builtin_fmaf(aff, __half2float(__high2half(h[3])), acc[7]);
    }
}

__global__ __launch_bounds__(NT, 4)
void softncuts_main(const float* __restrict__ batch,
                    const float* __restrict__ preds,
                    float* __restrict__ partials) {
    __shared__ float sB[NB];            // batch halo, f32
    __shared__ uint4 sPk[NB];           // preds halo, 8 x f16 packed per voxel
    __shared__ float sRed[8][16];

    const int bid  = blockIdx.x;
    const int bb   = bid >> 7;          // batch index 0..3
    const int tile = bid & 127;
    const int tw = tile & 3;            // -> w0 = tw*8
    const int th = (tile >> 2) & 3;     // -> h0 = th*8
    const int td = tile >> 4;           // -> d0 = td*4
    const int d0 = td * TD, h0 = th * TH, w0 = tw * TW;

    const int tid  = threadIdx.x;
    const int half = tid >> 8;          // 0/1, wave-uniform (waves 0-3 vs 4-7)
    const int vtid = tid & 255;
    const int lw = vtid & 7;            // 0..7
    const int lh = (vtid >> 3) & 7;     // 0..7
    const int ld = vtid >> 6;           // 0..3

    const float* bbase = batch + (size_t)bb * 32768;
    const float* pbase = preds + (size_t)bb * 8 * 32768;

    // ---- stage forward-x halo, float4-vectorized along w ----
    // chunk grid aligned to gw % 4 == 0: chunks start at w0-4+4c, hw = 4c-1+e.
    if (tid < NTASK) {
        const int t   = tid;
        const int c   = t & 3;
        const int row = t >> 2;
        const int hh  = row % HHh;
        const int hd  = row / HHh;
        const int gd  = d0 + hd;
        const int gh  = h0 + hh - 3;
        const int gw0 = w0 - 4 + c * 4;
        const int hwb = c * 4 - 1;
        const bool fast = (gd < 32) & ((unsigned)gh < 32u) & (gw0 >= 0) & (gw0 + 3 < 32);
        if (fast) {
            const int sidx = (gd * 32 + gh) * 32 + gw0;   // 16B-aligned
            float4 pv[9];
            pv[0] = *(const float4*)(bbase + sidx);
#pragma unroll
            for (int k = 0; k < 8; ++k)
                pv[k + 1] = *(const float4*)(pbase + sidx + k * 32768);
#pragma unroll
            for (int e = 0; e < 4; ++e) {
                const int hw = hwb + e;
                if (hw < 0 || hw >= HWh) continue;
                const int f = hd * SXB + hh * SYB + hw;
                sB[f] = ((const float*)&pv[0])[e];
                unsigned u[4];
#pragma unroll
                for (int k = 0; k < 4; ++k)
                    u[k] = pack2(((const float*)&pv[2 * k + 1])[e],
                                 ((const float*)&pv[2 * k + 2])[e]);
                sPk[f] = make_uint4(u[0], u[1], u[2], u[3]);
            }
        } else {
#pragma unroll
            for (int e = 0; e < 4; ++e) {
                const int hw = hwb + e;
                if (hw < 0 || hw >= HWh) continue;
                const int gw = gw0 + e;
                const bool in = (gd < 32) & ((unsigned)gh < 32u) & ((unsigned)gw < 32u);
                const int sidx = (gd * 32 + gh) * 32 + gw;
                const int f = hd * SXB + hh * SYB + hw;
                sB[f] = in ? bbase[sidx] : EPS_F;
                unsigned u[4];
#pragma unroll
                for (int k = 0; k < 4; ++k)
                    u[k] = pack2(in ? pbase[sidx + (2 * k) * 32768]     : 0.f,
                                 in ? pbase[sidx + (2 * k + 1) * 32768] : 0.f);
                sPk[f] = make_uint4(u[0], u[1], u[2], u[3]);
            }
        }
    }
    __syncthreads();

    // ---- own voxel values from GLOBAL f32 (full precision for b_own and q) ----
    const int gdo = d0 + ld, gho = h0 + lh, gwo = w0 + lw;
    const int sidx_own = (gdo * 32 + gho) * 32 + gwo;
    const float b_own = bbase[sidx_own];
    float q[8];
#pragma unroll
    for (int k = 0; k < 8; ++k) q[k] = pbase[sidx_own + k * 32768];

    const int vown = ld * SXB + (lh + 3) * SYB + (lw + 3);

    float acc[9];
#pragma unroll
    for (int i = 0; i < 9; ++i) acc[i] = 0.f;

    if (half == 0) accum_pairs<0>(sB, sPk, vown, b_own, acc);
    else           accum_pairs<1>(sB, sPk, vown, b_own, acc);

    // ---- geometric pad sum S over lexicographically NEGATIVE OOB offsets ----
    float S = 0.f;
    const bool border = (d0 < 3) | (h0 < 3) | (h0 + TH > 29) | (w0 < 3) | (w0 + TW > 29);
    if (border && half == 0) {
        constexpr float EXT[10] = {EX0, EX1, 0.f, 0.f, EX4, 0.f, 0.f, 0.f, 0.f, EX9};
        for (int dxi = 0; dxi < 7; ++dxi) {
            const int dx  = dxi - 3;
            const int dxx = dx * dx;
            const bool ind = (unsigned)(gdo + dx) < 32u;
            for (int dyi = 0; dyi < 7; ++dyi) {
                const int dy   = dyi - 3;
                const int c2xy = dxx + dy * dy;
                if (c2xy >= 16) continue;
                const float wxy = __expf((float)c2xy * -0.0625f);
                const bool inxy = ind & ((unsigned)(gho + dy) < 32u);
#pragma unroll
                for (int dzi = 0; dzi < 7; ++dzi) {
                    const int dz  = dzi - 3;
                    const int czz = dz * dz;
                    const bool neg = (dx < 0) || (dx == 0 && (dy < 0 || (dy == 0 && dz < 0)));
                    const bool valid = ((c2xy + czz) < 16) && neg;
                    const bool inall = inxy & ((unsigned)(gwo + dz) < 32u);
                    S += (valid && !inall) ? wxy * EXT[czz] : 0.f;
                }
            }
        }
    }
    const float db = b_own - EPS_F;
    const float selfpad = (half == 0) ? (1.f + S * __expf(db * db * -0.01f)) : 0.f;

    // ---- per-lane contributions (voxel shared by 2 threads; self terms once) ----
    float vals[16];
#pragma unroll
    for (int k = 0; k < 8; ++k) {
        vals[k]     = q[k] * (2.f * acc[k] + ((half == 0) ? q[k] : 0.f));
        vals[8 + k] = q[k] * (acc[8] + selfpad) + acc[k];
    }

#pragma unroll
    for (int i = 0; i < 16; ++i) {
        float s = vals[i];
        for (int off = 32; off; off >>= 1) s += __shfl_down(s, off);
        vals[i] = s;
    }
    const int wave = tid >> 6;
    const int lane = tid & 63;
    if (lane == 0) {
#pragma unroll
        for (int i = 0; i < 16; ++i) sRed[wave][i] = vals[i];
    }
    __syncthreads();
    if (tid < 16) {
        float s = 0.f;
#pragma unroll
        for (int w = 0; w < 8; ++w) s += sRed[w][tid];
        partials[tid * NBLK + bid] = s;
    }
}

__global__ __launch_bounds__(1024)
void softncuts_finalize(const float* __restrict__ partials,
                        float* __restrict__ out) {
    __shared__ float red[64];
    const int tid = threadIdx.x;          // 0..1023
    const int group = tid >> 4;           // 0..63 = bb*16 + slot
    const int j0 = tid & 15;
    const int slot = group & 15;
    const int bb = group >> 4;

    const float* p = partials + slot * NBLK + bb * 128;   // 128 tiles per batch
    float s = 0.f;
#pragma unroll
    for (int k = 0; k < 8; ++k) s += p[j0 + 16 * k];
    for (int off = 8; off; off >>= 1) s += __shfl_down(s, off, 16);
    if (j0 == 0) red[group] = s;
    __syncthreads();

    if (tid < 4) {
        float accv = 0.f;
#pragma unroll
        for (int k = 0; k < 8; ++k)
            accv += red[tid * 16 + k] / red[tid * 16 + 8 + k];
        out[tid] = 8.0f - accv;
    }
}

extern "C" void kernel_launch(void* const* d_in, const int* in_sizes, int n_in,
                              void* d_out, int out_size, void* d_ws, size_t ws_size,
                              hipStream_t stream) {
    const float* batch = (const float*)d_in[0];
    const float* preds = (const float*)d_in[1];
    float* out      = (float*)d_out;
    float* partials = (float*)d_ws;   // 16*NBLK floats = 32 KB

    softncuts_main<<<dim3(NBLK), dim3(NT), 0, stream>>>(batch, preds, partials);
    softncuts_finalize<<<dim3(1), dim3(1024), 0, stream>>>(partials, out);
}